// Round 1
// baseline (754.778 us; speedup 1.0000x reference)
//
#include <hip/hip_runtime.h>

typedef __attribute__((ext_vector_type(4))) float floatx4;
typedef __attribute__((ext_vector_type(8))) short short8;

#define AS1(p) ((const __attribute__((address_space(1))) unsigned int*)(p))
#define AS3(p) ((__attribute__((address_space(3))) unsigned int*)(p))

static __device__ __forceinline__ void async16(const void* g, void* l) {
  __builtin_amdgcn_global_load_lds(AS1(g), AS3(l), 16, 0, 0);
}

static __device__ __forceinline__ unsigned short f2bf(float f) {
  unsigned u = __float_as_uint(f);
  unsigned r = u + 0x7FFFu + ((u >> 16) & 1u);
  return (unsigned short)(r >> 16);
}
static __device__ __forceinline__ float bf2f(unsigned short h) {
  return __uint_as_float(((unsigned)h) << 16);
}
static __device__ __forceinline__ float bf_lo(unsigned u) { return __uint_as_float(u << 16); }
static __device__ __forceinline__ float bf_hi(unsigned u) { return __uint_as_float(u & 0xFFFF0000u); }

static __device__ __forceinline__ float actf(float v) {
  float a = v >= 0.f ? v : 0.2f * v;
  a *= 1.41421356237309515f;
  return fminf(fmaxf(a, -256.f), 256.f);
}

// ---------------------------------------------------------------- styles
// styles[b,c] = sum_d w[b,d]*aw[c,d] * (1/sqrt(512)) + ab[c]
__global__ void k_styles(const float* __restrict__ w, const float* __restrict__ aw,
                         const float* __restrict__ ab, float* __restrict__ styles) {
  int t = blockIdx.x * 256 + threadIdx.x;   // 4096
  int b = t >> 9, c = t & 511;
  float acc = 0.f;
  for (int d = 0; d < 512; ++d) acc += w[b * 512 + d] * aw[c * 512 + d];
  styles[t] = acc * 0.04419417382415922f + ab[c];
}

// ---------------------------------------------------------------- msr = rsqrt(mean(styles^2))
__global__ void k_msr(const float* __restrict__ styles, float* __restrict__ msr) {
  __shared__ float red[256];
  float acc = 0.f;
  for (int i = threadIdx.x; i < 4096; i += 256) { float v = styles[i]; acc += v * v; }
  red[threadIdx.x] = acc; __syncthreads();
  for (int s = 128; s > 0; s >>= 1) {
    if ((int)threadIdx.x < s) red[threadIdx.x] += red[threadIdx.x + s];
    __syncthreads();
  }
  if (threadIdx.x == 0) *msr = rsqrtf(red[0] / 4096.0f);
}

// ---------------------------------------------------------------- per-o weight stats
// q[o,i] = sum_k cw[o,i,k]^2 ; t[o] = rsqrt(mean over 4608)
__global__ void k_wstat(const float* __restrict__ cw, float* __restrict__ t, float* __restrict__ q) {
  int o = blockIdx.x, tid = threadIdx.x;
  __shared__ float red[256];
  float tot = 0.f;
  for (int i = tid; i < 512; i += 256) {
    const float* p = cw + ((size_t)o * 512 + i) * 9;
    float s = 0.f;
#pragma unroll
    for (int k = 0; k < 9; ++k) s += p[k] * p[k];
    q[o * 512 + i] = s;
    tot += s;
  }
  red[tid] = tot; __syncthreads();
  for (int s2 = 128; s2 > 0; s2 >>= 1) {
    if (tid < s2) red[tid] += red[tid + s2];
    __syncthreads();
  }
  if (tid == 0) t[o] = rsqrtf(red[0] / 4608.0f);
}

// ---------------------------------------------------------------- g[b,o] = t[o]*rsqrt(t^2*sum_i s^2*q + 1e-8)
__global__ void k_dmod(const float* __restrict__ styles, const float* __restrict__ msr,
                       const float* __restrict__ t, const float* __restrict__ q,
                       float* __restrict__ g) {
  int idx = blockIdx.x * 256 + threadIdx.x;  // 4096
  int b = idx >> 9, o = idx & 511;
  float m = *msr;
  float acc = 0.f;
  for (int i = 0; i < 512; ++i) {
    float s = styles[b * 512 + i] * m;
    acc += s * s * q[o * 512 + i];
  }
  float to = t[o];
  g[idx] = to * rsqrtf(to * to * acc + 1e-8f);
}

// ---------------------------------------------------------------- wbf[b][o][s][i] = bf16(cw[o,i,s] * g[b,o] * styles[b,i]*msr)
__global__ __launch_bounds__(256) void k_wpack(const float* __restrict__ cw,
                                               const float* __restrict__ styles,
                                               const float* __restrict__ msr,
                                               const float* __restrict__ g,
                                               unsigned short* __restrict__ wbf) {
  __shared__ float raw[512][11];
  int o = blockIdx.x, tid = threadIdx.x;
  for (int i = tid; i < 512; i += 256) {
    const float* p = cw + ((size_t)o * 512 + i) * 9;
#pragma unroll
    for (int k = 0; k < 9; ++k) raw[i][k] = p[k];
  }
  __syncthreads();
  float m = *msr;
  for (int b = 0; b < 8; ++b) {
    float gg = g[b * 512 + o];
    for (int f = tid; f < 9 * 512; f += 256) {
      int s = f >> 9, i = f & 511;
      float v = raw[i][s] * gg * (styles[b * 512 + i] * m);
      wbf[((((size_t)b * 512 + o) * 9 + s) << 9) + i] = f2bf(v);
    }
  }
}

// ---------------------------------------------------------------- xp[b][Y][X][c] NHWC bf16 zero-padded (+2)
__global__ __launch_bounds__(256) void k_xpack(const float* __restrict__ x,
                                               unsigned short* __restrict__ xp) {
  __shared__ float tile[64][65];
  int Y = blockIdx.x, cc0 = blockIdx.y * 64, b = blockIdx.z;
  int tid = threadIdx.x;
  int yy = Y - 2;
  bool valid = (yy >= 0 && yy < 64);
  if (valid) {
    for (int it = 0; it < 16; ++it) {
      int f = it * 256 + tid;
      int cc = f >> 6, xx = f & 63;
      tile[xx][cc] = x[(((size_t)b * 512 + cc0 + cc) * 64 + yy) * 64 + xx];
    }
  }
  __syncthreads();
  for (int it = 0; it < 17; ++it) {
    int f = it * 256 + tid;   // < 68*64
    int X = f >> 6, cc = f & 63;
    int xx = X - 2;
    float v = (valid && xx >= 0 && xx < 64) ? tile[xx][cc] : 0.f;
    xp[(((size_t)b * 68 + Y) * 68 + X) * 512 + cc0 + cc] = f2bf(v);
  }
}

// ---------------------------------------------------------------- implicit-GEMM conv (bf16 MFMA)
// C[p][o] = sum_{s,i} xp[b][oy+ky][ox+kx][i] * wbf[b][o][s][i]; y layout [b][o][p], p=oy*66+ox
__global__ __launch_bounds__(256) void k_conv(const unsigned short* __restrict__ xp,
                                              const unsigned short* __restrict__ wbf,
                                              const float* __restrict__ cb,
                                              float* __restrict__ y) {
  __shared__ __align__(16) unsigned short Abuf[128 * 32];
  __shared__ __align__(16) unsigned short Bbuf[128 * 32];
  const int tid = threadIdx.x;
  const int w = tid >> 6;
  const int lane = tid & 63;
  const int m0 = blockIdx.x * 128;
  const int n0 = blockIdx.y * 128;
  const int b = blockIdx.z;
  const int wm = w & 1, wn = w >> 1;

  const int rowA = (w << 4) + (lane >> 2);
  const int chunk = lane & 3;
  int p0 = m0 + rowA;      if (p0 > 4355) p0 = 4355;
  int p1 = m0 + rowA + 64; if (p1 > 4355) p1 = 4355;
  const int oy0 = p0 / 66, ox0 = p0 - oy0 * 66;
  const int oy1 = p1 / 66, ox1 = p1 - oy1 * 66;
  const unsigned short* xpb = xp + (size_t)b * (68 * 68 * 512);
  const size_t a0 = ((size_t)(oy0 * 68 + ox0)) * 512 + chunk * 8;
  const size_t a1 = ((size_t)(oy1 * 68 + ox1)) * 512 + chunk * 8;
  const size_t b0 = (((size_t)b * 512 + (n0 + rowA)) * 9) * 512 + chunk * 8;
  const size_t b1 = (((size_t)b * 512 + (n0 + rowA + 64)) * 9) * 512 + chunk * 8;

  unsigned short* aDst0 = &Abuf[(w * 16) * 32];
  unsigned short* aDst1 = &Abuf[(64 + w * 16) * 32];
  unsigned short* bDst0 = &Bbuf[(w * 16) * 32];
  unsigned short* bDst1 = &Bbuf[(64 + w * 16) * 32];

  const int fr = lane & 15;
  const int fq = (lane >> 4) * 8;

  floatx4 acc[4][4];
#pragma unroll
  for (int i = 0; i < 4; ++i)
#pragma unroll
    for (int j = 0; j < 4; ++j) acc[i][j] = (floatx4){0.f, 0.f, 0.f, 0.f};

  for (int ic = 0; ic < 16; ++ic) {
    const int ko = ic * 32;
#pragma unroll
    for (int s = 0; s < 9; ++s) {
      const int ky = s / 3, kx = s - (s / 3) * 3;
      const int sh = (ky * 68 + kx) * 512;
      __syncthreads();
      async16(xpb + a0 + sh + ko, aDst0);
      async16(xpb + a1 + sh + ko, aDst1);
      async16(wbf + b0 + s * 512 + ko, bDst0);
      async16(wbf + b1 + s * 512 + ko, bDst1);
      asm volatile("s_waitcnt vmcnt(0)" ::: "memory");
      __syncthreads();
      short8 aF[4], bF[4];
#pragma unroll
      for (int mi = 0; mi < 4; ++mi)
        aF[mi] = *(const short8*)&Abuf[(wm * 64 + mi * 16 + fr) * 32 + fq];
#pragma unroll
      for (int ni = 0; ni < 4; ++ni)
        bF[ni] = *(const short8*)&Bbuf[(wn * 64 + ni * 16 + fr) * 32 + fq];
#pragma unroll
      for (int mi = 0; mi < 4; ++mi)
#pragma unroll
        for (int ni = 0; ni < 4; ++ni)
          acc[mi][ni] = __builtin_amdgcn_mfma_f32_16x16x32_bf16(aF[mi], bF[ni], acc[mi][ni], 0, 0, 0);
    }
  }

  const int lr = (lane >> 4) * 4;
  const int lc = lane & 15;
  float cbv[4];
#pragma unroll
  for (int ni = 0; ni < 4; ++ni) cbv[ni] = cb[n0 + wn * 64 + ni * 16 + lc];
#pragma unroll
  for (int mi = 0; mi < 4; ++mi) {
#pragma unroll
    for (int r = 0; r < 4; ++r) {
      const int p = m0 + wm * 64 + mi * 16 + lr + r;
      if (p < 4356) {
#pragma unroll
        for (int ni = 0; ni < 4; ++ni) {
          const int o = n0 + wn * 64 + ni * 16 + lc;
          y[((size_t)b * 512 + o) * 4356 + p] = acc[mi][ni][r] + cbv[ni];
        }
      }
    }
  }
}

// ---------------------------------------------------------------- fused up-y, up-x, act, down-y, down-x per plane
__global__ __launch_bounds__(256) void k_updown(const float* __restrict__ yg,
                                                const float* __restrict__ uf,
                                                const float* __restrict__ df,
                                                float* __restrict__ out) {
  __shared__ __align__(16) unsigned short t1t2[64 * 144];   // t1: 138*66=9108 (<=9216); later t2 bf16 64*144
  __shared__ __align__(16) unsigned short zbuf[138 * 144];  // z bf16, row pitch 144
  const int tid = threadIdx.x;
  const int plane = blockIdx.x;
  const float* yp = yg + (size_t)plane * 4356;
  float fuw[12], fdw[12];
#pragma unroll
  for (int i = 0; i < 12; ++i) { fuw[i] = uf[11 - i] * 2.0f; fdw[i] = df[11 - i]; }

  // Stage B: t1[Y][x] (up-y), even/odd Y pair share taps. reads y from global (L1/L2 resident)
  for (int t = tid; t < 69 * 66; t += 256) {
    int v = t / 66, xx = t - v * 66;
    float ae = 0.f, ao = 0.f;
#pragma unroll
    for (int u = 0; u < 6; ++u) {
      int r = v + u - 4;
      float yv = (r >= 0 && r < 66) ? yp[r * 66 + xx] : 0.f;
      ae += yv * fuw[2 * u + 1];
      ao += yv * fuw[2 * u];
    }
    t1t2[(2 * v) * 66 + xx] = f2bf(ae);
    t1t2[(2 * v + 1) * 66 + xx] = f2bf(ao);
  }
  __syncthreads();

  // Stage C: z[Y][X] = act(up-x(t1)), X pairs share taps; packed bf16x2 stores
  for (int t = tid; t < 138 * 69; t += 256) {
    int Y = t / 69, h = t - Y * 69;
    float ae = 0.f, ao = 0.f;
#pragma unroll
    for (int u = 0; u < 6; ++u) {
      int c = h + u - 4;
      float tv = (c >= 0 && c < 66) ? bf2f(t1t2[Y * 66 + c]) : 0.f;
      ae += tv * fuw[2 * u + 1];
      ao += tv * fuw[2 * u];
    }
    ae = actf(ae); ao = actf(ao);
    unsigned pack = (unsigned)f2bf(ae) | ((unsigned)f2bf(ao) << 16);
    *(unsigned*)&zbuf[Y * 144 + 2 * h] = pack;
  }
  __syncthreads();

  // Stage D: t2[y][X] = down-y(z), row-wise b128 reads of z, 8 X per task; t2 overwrites t1 region
  for (int t = tid; t < 64 * 18; t += 256) {
    int yr = t / 18, cx = t - yr * 18;
    int X0 = cx * 8;
    float acc[8];
#pragma unroll
    for (int e = 0; e < 8; ++e) acc[e] = 0.f;
#pragma unroll
    for (int i = 0; i < 12; ++i) {
      uint4 zv = *(const uint4*)&zbuf[(2 * yr + i) * 144 + X0];
      float c = fdw[i];
      acc[0] += c * bf_lo(zv.x); acc[1] += c * bf_hi(zv.x);
      acc[2] += c * bf_lo(zv.y); acc[3] += c * bf_hi(zv.y);
      acc[4] += c * bf_lo(zv.z); acc[5] += c * bf_hi(zv.z);
      acc[6] += c * bf_lo(zv.w); acc[7] += c * bf_hi(zv.w);
    }
    uint4 st;
    st.x = (unsigned)f2bf(acc[0]) | ((unsigned)f2bf(acc[1]) << 16);
    st.y = (unsigned)f2bf(acc[2]) | ((unsigned)f2bf(acc[3]) << 16);
    st.z = (unsigned)f2bf(acc[4]) | ((unsigned)f2bf(acc[5]) << 16);
    st.w = (unsigned)f2bf(acc[6]) | ((unsigned)f2bf(acc[7]) << 16);
    *(uint4*)&t1t2[yr * 144 + X0] = st;
  }
  __syncthreads();

  // Stage E: out[y][x] = down-x(t2), coalesced 256B row stores
  for (int t = tid; t < 4096; t += 256) {
    int yr = t >> 6, xx = t & 63;
    float acc = 0.f;
#pragma unroll
    for (int j = 0; j < 12; j += 2) {
      unsigned pv = *(const unsigned*)&t1t2[yr * 144 + 2 * xx + j];
      acc += fdw[j] * bf_lo(pv) + fdw[j + 1] * bf_hi(pv);
    }
    out[(size_t)plane * 4096 + t] = acc;
  }
}

extern "C" void kernel_launch(void* const* d_in, const int* in_sizes, int n_in,
                              void* d_out, int out_size, void* d_ws, size_t ws_size,
                              hipStream_t stream) {
  const float* x  = (const float*)d_in[0];
  const float* w  = (const float*)d_in[1];
  const float* aw = (const float*)d_in[2];
  const float* ab = (const float*)d_in[3];
  const float* cw = (const float*)d_in[4];
  const float* cb = (const float*)d_in[5];
  const float* uf = (const float*)d_in[6];
  const float* df = (const float*)d_in[7];
  float* out = (float*)d_out;
  char* ws = (char*)d_ws;

  float* styles = (float*)(ws + 0);                 // 16384
  float* msr    = (float*)(ws + 16384);             // 256
  float* tbuf   = (float*)(ws + 16640);             // 2048
  float* qbuf   = (float*)(ws + 18688);             // 1 MiB
  float* gbuf   = (float*)(ws + 1067264);           // 16384
  unsigned short* xp  = (unsigned short*)(ws + 1083648);   // 37,879,808 B
  unsigned short* wbf = (unsigned short*)(ws + 38963456);  // 37,748,736 B
  float* yb           = (float*)(ws + 76712192);           // 71,368,704 B

  k_styles<<<16, 256, 0, stream>>>(w, aw, ab, styles);
  k_msr<<<1, 256, 0, stream>>>(styles, msr);
  k_wstat<<<512, 256, 0, stream>>>(cw, tbuf, qbuf);
  k_dmod<<<16, 256, 0, stream>>>(styles, msr, tbuf, qbuf, gbuf);
  k_wpack<<<512, 256, 0, stream>>>(cw, styles, msr, gbuf, wbf);
  k_xpack<<<dim3(68, 8, 8), 256, 0, stream>>>(x, xp);
  k_conv<<<dim3(35, 4, 8), 256, 0, stream>>>(xp, wbf, cb, yb);
  k_updown<<<4096, 256, 0, stream>>>(yb, uf, df, out);
}

// Round 2
// 657.512 us; speedup vs baseline: 1.1479x; 1.1479x over previous
//
#include <hip/hip_runtime.h>

typedef __attribute__((ext_vector_type(4))) float floatx4;
typedef __attribute__((ext_vector_type(8))) short short8;

#define AS1(p) ((const __attribute__((address_space(1))) unsigned int*)(p))
#define AS3(p) ((__attribute__((address_space(3))) unsigned int*)(p))

static __device__ __forceinline__ void async16(const void* g, void* l) {
  __builtin_amdgcn_global_load_lds(AS1(g), AS3(l), 16, 0, 0);
}

static __device__ __forceinline__ unsigned short f2bf(float f) {
  unsigned u = __float_as_uint(f);
  unsigned r = u + 0x7FFFu + ((u >> 16) & 1u);
  return (unsigned short)(r >> 16);
}
static __device__ __forceinline__ float bf2f(unsigned short h) {
  return __uint_as_float(((unsigned)h) << 16);
}
static __device__ __forceinline__ float bf_lo(unsigned u) { return __uint_as_float(u << 16); }
static __device__ __forceinline__ float bf_hi(unsigned u) { return __uint_as_float(u & 0xFFFF0000u); }

static __device__ __forceinline__ float actf(float v) {
  float a = v >= 0.f ? v : 0.2f * v;
  a *= 1.41421356237309515f;
  return fminf(fmaxf(a, -256.f), 256.f);
}

// ---------------------------------------------------------------- styles
__global__ void k_styles(const float* __restrict__ w, const float* __restrict__ aw,
                         const float* __restrict__ ab, float* __restrict__ styles) {
  int t = blockIdx.x * 256 + threadIdx.x;   // 4096
  int b = t >> 9, c = t & 511;
  float acc = 0.f;
  for (int d = 0; d < 512; ++d) acc += w[b * 512 + d] * aw[c * 512 + d];
  styles[t] = acc * 0.04419417382415922f + ab[c];
}

// ---------------------------------------------------------------- msr = rsqrt(mean(styles^2))
__global__ void k_msr(const float* __restrict__ styles, float* __restrict__ msr) {
  __shared__ float red[256];
  float acc = 0.f;
  for (int i = threadIdx.x; i < 4096; i += 256) { float v = styles[i]; acc += v * v; }
  red[threadIdx.x] = acc; __syncthreads();
  for (int s = 128; s > 0; s >>= 1) {
    if ((int)threadIdx.x < s) red[threadIdx.x] += red[threadIdx.x + s];
    __syncthreads();
  }
  if (threadIdx.x == 0) *msr = rsqrtf(red[0] / 4096.0f);
}

// ---------------------------------------------------------------- per-o weight stats
__global__ void k_wstat(const float* __restrict__ cw, float* __restrict__ t, float* __restrict__ q) {
  int o = blockIdx.x, tid = threadIdx.x;
  __shared__ float red[256];
  float tot = 0.f;
  for (int i = tid; i < 512; i += 256) {
    const float* p = cw + ((size_t)o * 512 + i) * 9;
    float s = 0.f;
#pragma unroll
    for (int k = 0; k < 9; ++k) s += p[k] * p[k];
    q[o * 512 + i] = s;
    tot += s;
  }
  red[tid] = tot; __syncthreads();
  for (int s2 = 128; s2 > 0; s2 >>= 1) {
    if (tid < s2) red[tid] += red[tid + s2];
    __syncthreads();
  }
  if (tid == 0) t[o] = rsqrtf(red[0] / 4608.0f);
}

// ---------------------------------------------------------------- g[b,o]
__global__ void k_dmod(const float* __restrict__ styles, const float* __restrict__ msr,
                       const float* __restrict__ t, const float* __restrict__ q,
                       float* __restrict__ g) {
  int idx = blockIdx.x * 256 + threadIdx.x;  // 4096
  int b = idx >> 9, o = idx & 511;
  float m = *msr;
  float acc = 0.f;
  for (int i = 0; i < 512; ++i) {
    float s = styles[b * 512 + i] * m;
    acc += s * s * q[o * 512 + i];
  }
  float to = t[o];
  g[idx] = to * rsqrtf(to * to * acc + 1e-8f);
}

// ---------------------------------------------------------------- wbf2: fragment-order packed bf16 weights
// wbf2 idx = (((((b*4+nb)*2+wn)*9+s)*16+ic)*4+ni)*512 + (q*16+ol)*8 + j
// where o = nb*128+wn*64+ni*16+ol, i = ic*32+q*8+j
__global__ __launch_bounds__(256) void k_wpack(const float* __restrict__ cw,
                                               const float* __restrict__ styles,
                                               const float* __restrict__ msr,
                                               const float* __restrict__ g,
                                               unsigned short* __restrict__ wbf2) {
  __shared__ float raw[512][11];
  int o = blockIdx.x, tid = threadIdx.x;
  for (int i = tid; i < 512; i += 256) {
    const float* p = cw + ((size_t)o * 512 + i) * 9;
#pragma unroll
    for (int k = 0; k < 9; ++k) raw[i][k] = p[k];
  }
  __syncthreads();
  float m = *msr;
  const int nb = o >> 7, wn = (o >> 6) & 1, ni = (o >> 4) & 3, ol = o & 15;
  for (int b = 0; b < 8; ++b) {
    float gg = g[b * 512 + o];
    const size_t base_bo = ((size_t)(b * 4 + nb) * 2 + wn);
    for (int f = tid; f < 9 * 512; f += 256) {
      int s = f >> 9, i = f & 511;
      int ic = i >> 5, qq = (i >> 3) & 3, j = i & 7;
      float v = raw[i][s] * gg * (styles[b * 512 + i] * m);
      size_t idx = ((((base_bo * 9 + s) * 16 + ic) * 4 + ni) * 512) + (qq * 16 + ol) * 8 + j;
      wbf2[idx] = f2bf(v);
    }
  }
}

// ---------------------------------------------------------------- xp[b][Y][X][c] NHWC bf16 zero-padded (+2)
__global__ __launch_bounds__(256) void k_xpack(const float* __restrict__ x,
                                               unsigned short* __restrict__ xp) {
  __shared__ float tile[64][65];
  int Y = blockIdx.x, cc0 = blockIdx.y * 64, b = blockIdx.z;
  int tid = threadIdx.x;
  int yy = Y - 2;
  bool valid = (yy >= 0 && yy < 64);
  if (valid) {
    for (int it = 0; it < 16; ++it) {
      int f = it * 256 + tid;
      int cc = f >> 6, xx = f & 63;
      tile[xx][cc] = x[(((size_t)b * 512 + cc0 + cc) * 64 + yy) * 64 + xx];
    }
  }
  __syncthreads();
  for (int it = 0; it < 17; ++it) {
    int f = it * 256 + tid;   // < 68*64
    int X = f >> 6, cc = f & 63;
    int xx = X - 2;
    float v = (valid && xx >= 0 && xx < 64) ? tile[xx][cc] : 0.f;
    xp[(((size_t)b * 68 + Y) * 68 + X) * 512 + cc0 + cc] = f2bf(v);
  }
}

// ---------------------------------------------------------------- patch-based implicit-GEMM conv
// Patch: 5 input rows x 68 px x 32 ch per K-chunk, double-buffered, chunk-XOR swizzled.
// B streamed global->registers from wbf2 (coalesced 1KB/wave-frag). One barrier per ic.
__global__ __launch_bounds__(256, 2) void k_conv(const unsigned short* __restrict__ xp,
                                                 const unsigned short* __restrict__ wbf2,
                                                 const float* __restrict__ cb,
                                                 float* __restrict__ y) {
  // 2 patch bufs x 384 vecs x 32 shorts = 24576 shorts = 49152 B
  __shared__ __align__(16) unsigned short lds[24576];
  const int tid = threadIdx.x;
  const int w = tid >> 6, lane = tid & 63;
  const int wm = w & 1, wn = w >> 1;
  const int q = lane >> 4, ln = lane & 15;

  // XCD-aware block decode: same (nt,b) weight stripe stays on one XCD
  const int xcd = blockIdx.x & 7;
  const int slot = blockIdx.x >> 3;
  const int combo = xcd * 4 + slot / 35;
  const int mt = slot % 35;
  const int nt = combo & 3;
  const int b = combo >> 2;
  const int m0 = mt * 128, n0 = nt * 128;
  const int oy0 = m0 / 66;

  const unsigned short* xpb = xp + (size_t)b * (68 * 68 * 512);

  // patch staging: 6 instrs/wave, 16 vecs each (384 slots cover 340 real vecs)
  size_t gof_p[6];
#pragma unroll
  for (int i = 0; i < 6; ++i) {
    int pv = w * 96 + i * 16 + (lane >> 2);
    int pve = pv < 339 ? pv : 339;
    int r = pve / 68, px = pve - r * 68;
    int Y = oy0 + r; if (Y > 67) Y = 67;
    int ch = ((lane & 3) ^ ((pve >> 1) & 3)) * 8;   // chunk-XOR swizzle (writer side)
    gof_p[i] = (size_t)(Y * 68 + px) * 512 + ch;
  }

  // A-frag pixel bases
  int pvA[4];
#pragma unroll
  for (int mi = 0; mi < 4; ++mi) {
    int p = m0 + wm * 64 + mi * 16 + ln; if (p > 4355) p = 4355;
    int oy = p / 66, ox = p - oy * 66;
    pvA[mi] = (oy - oy0) * 68 + ox;
  }

  // B fragment base (wave-level): coalesced packed layout
  const unsigned short* wB = wbf2 + (((size_t)(b * 4 + nt) * 2 + wn) * 294912) + (size_t)lane * 8;

  floatx4 acc[4][4];
#pragma unroll
  for (int i = 0; i < 4; ++i)
#pragma unroll
    for (int j = 0; j < 4; ++j) acc[i][j] = (floatx4){0.f, 0.f, 0.f, 0.f};

  unsigned short* pat0 = lds;
  unsigned short* pat1 = lds + 12288;

  // prologue: patch(0) + bF(ic=0,s=0)
#pragma unroll
  for (int i = 0; i < 6; ++i)
    async16(xpb + gof_p[i], pat0 + (w * 96 + i * 16) * 32);

  short8 bF[4];
#pragma unroll
  for (int ni = 0; ni < 4; ++ni)
    bF[ni] = *(const short8*)(wB + ni * 512);

  for (int ic = 0; ic < 16; ++ic) {
    asm volatile("s_waitcnt vmcnt(0)" ::: "memory");
    asm volatile("s_barrier" ::: "memory");
    const unsigned short* pb = (ic & 1) ? pat1 : pat0;
    unsigned short* pn = (ic & 1) ? pat0 : pat1;
    const size_t pchan = (size_t)(ic + 1) * 32;
#pragma unroll
    for (int s = 0; s < 9; ++s) {
      // spread next-patch staging over slots 1..6
      if (s >= 1 && s <= 6 && ic < 15)
        async16(xpb + gof_p[s - 1] + pchan, pn + (w * 96 + (s - 1) * 16) * 32);
      // prefetch next slot's B frags (registers; compiler-managed waits)
      const int sn = (s < 8) ? s + 1 : 0;
      const int icn = (s < 8) ? ic : (ic < 15 ? ic + 1 : 15);
      const unsigned short* wBn = wB + ((size_t)sn * 16 + icn) * 2048;
      short8 bN[4];
#pragma unroll
      for (int ni = 0; ni < 4; ++ni) bN[ni] = *(const short8*)(wBn + ni * 512);
      // A frags from patch (tap shift), XOR-swizzled chunks
      const int d = (s / 3) * 68 + (s % 3);
      short8 aF[4];
#pragma unroll
      for (int mi = 0; mi < 4; ++mi) {
        int pv = pvA[mi] + d;
        int off = pv * 32 + ((q ^ ((pv >> 1) & 3)) << 3);
        aF[mi] = *(const short8*)(pb + off);
      }
#pragma unroll
      for (int mi = 0; mi < 4; ++mi)
#pragma unroll
        for (int ni = 0; ni < 4; ++ni)
          acc[mi][ni] = __builtin_amdgcn_mfma_f32_16x16x32_bf16(aF[mi], bF[ni], acc[mi][ni], 0, 0, 0);
#pragma unroll
      for (int ni = 0; ni < 4; ++ni) bF[ni] = bN[ni];
    }
  }

  // ---------------- epilogue: LDS transpose -> 256B-contiguous stores
  __syncthreads();
  float* slab = (float*)lds + w * 2176;   // 32 o-rows x 68 pitch per wave
  const int pbase = m0 + wm * 64;
  const bool pok = (pbase + ln * 4) < 4356;
  float cbv[4];
#pragma unroll
  for (int ni = 0; ni < 4; ++ni) cbv[ni] = cb[n0 + wn * 64 + ni * 16 + ln];

#pragma unroll
  for (int pass = 0; pass < 2; ++pass) {
#pragma unroll
    for (int ni2 = 0; ni2 < 2; ++ni2) {
      const int ni = pass * 2 + ni2;
#pragma unroll
      for (int mi = 0; mi < 4; ++mi) {
        float4 v;
        v.x = acc[mi][ni][0] + cbv[ni];
        v.y = acc[mi][ni][1] + cbv[ni];
        v.z = acc[mi][ni][2] + cbv[ni];
        v.w = acc[mi][ni][3] + cbv[ni];
        *(float4*)&slab[(ni2 * 16 + ln) * 68 + mi * 16 + q * 4] = v;
      }
    }
#pragma unroll
    for (int i = 0; i < 8; ++i) {
      const int orow = i * 4 + q;             // 0..31 within pass
      const int o = n0 + wn * 64 + pass * 32 + orow;
      if (pok) {
        float4 vv = *(const float4*)&slab[orow * 68 + ln * 4];
        *(float4*)&y[((size_t)b * 512 + o) * 4356 + pbase + ln * 4] = vv;
      }
    }
  }
}

// ---------------------------------------------------------------- fused up/act/down per plane
__global__ __launch_bounds__(256) void k_updown(const float* __restrict__ yg,
                                                const float* __restrict__ uf,
                                                const float* __restrict__ df,
                                                float* __restrict__ out) {
  __shared__ __align__(16) unsigned short t1t2[64 * 144];
  __shared__ __align__(16) unsigned short zbuf[138 * 144];
  const int tid = threadIdx.x;
  const int plane = blockIdx.x;
  const float* yp = yg + (size_t)plane * 4356;
  float fuw[12], fdw[12];
#pragma unroll
  for (int i = 0; i < 12; ++i) { fuw[i] = uf[11 - i] * 2.0f; fdw[i] = df[11 - i]; }

  for (int t = tid; t < 69 * 66; t += 256) {
    int v = t / 66, xx = t - v * 66;
    float ae = 0.f, ao = 0.f;
#pragma unroll
    for (int u = 0; u < 6; ++u) {
      int r = v + u - 4;
      float yv = (r >= 0 && r < 66) ? yp[r * 66 + xx] : 0.f;
      ae += yv * fuw[2 * u + 1];
      ao += yv * fuw[2 * u];
    }
    t1t2[(2 * v) * 66 + xx] = f2bf(ae);
    t1t2[(2 * v + 1) * 66 + xx] = f2bf(ao);
  }
  __syncthreads();

  for (int t = tid; t < 138 * 69; t += 256) {
    int Y = t / 69, h = t - Y * 69;
    float ae = 0.f, ao = 0.f;
#pragma unroll
    for (int u = 0; u < 6; ++u) {
      int c = h + u - 4;
      float tv = (c >= 0 && c < 66) ? bf2f(t1t2[Y * 66 + c]) : 0.f;
      ae += tv * fuw[2 * u + 1];
      ao += tv * fuw[2 * u];
    }
    ae = actf(ae); ao = actf(ao);
    unsigned pack = (unsigned)f2bf(ae) | ((unsigned)f2bf(ao) << 16);
    *(unsigned*)&zbuf[Y * 144 + 2 * h] = pack;
  }
  __syncthreads();

  for (int t = tid; t < 64 * 18; t += 256) {
    int yr = t / 18, cx = t - yr * 18;
    int X0 = cx * 8;
    float acc[8];
#pragma unroll
    for (int e = 0; e < 8; ++e) acc[e] = 0.f;
#pragma unroll
    for (int i = 0; i < 12; ++i) {
      uint4 zv = *(const uint4*)&zbuf[(2 * yr + i) * 144 + X0];
      float c = fdw[i];
      acc[0] += c * bf_lo(zv.x); acc[1] += c * bf_hi(zv.x);
      acc[2] += c * bf_lo(zv.y); acc[3] += c * bf_hi(zv.y);
      acc[4] += c * bf_lo(zv.z); acc[5] += c * bf_hi(zv.z);
      acc[6] += c * bf_lo(zv.w); acc[7] += c * bf_hi(zv.w);
    }
    uint4 st;
    st.x = (unsigned)f2bf(acc[0]) | ((unsigned)f2bf(acc[1]) << 16);
    st.y = (unsigned)f2bf(acc[2]) | ((unsigned)f2bf(acc[3]) << 16);
    st.z = (unsigned)f2bf(acc[4]) | ((unsigned)f2bf(acc[5]) << 16);
    st.w = (unsigned)f2bf(acc[6]) | ((unsigned)f2bf(acc[7]) << 16);
    *(uint4*)&t1t2[yr * 144 + X0] = st;
  }
  __syncthreads();

  for (int t = tid; t < 4096; t += 256) {
    int yr = t >> 6, xx = t & 63;
    float acc = 0.f;
#pragma unroll
    for (int j = 0; j < 12; j += 2) {
      unsigned pv = *(const unsigned*)&t1t2[yr * 144 + 2 * xx + j];
      acc += fdw[j] * bf_lo(pv) + fdw[j + 1] * bf_hi(pv);
    }
    out[(size_t)plane * 4096 + t] = acc;
  }
}

extern "C" void kernel_launch(void* const* d_in, const int* in_sizes, int n_in,
                              void* d_out, int out_size, void* d_ws, size_t ws_size,
                              hipStream_t stream) {
  const float* x  = (const float*)d_in[0];
  const float* w  = (const float*)d_in[1];
  const float* aw = (const float*)d_in[2];
  const float* ab = (const float*)d_in[3];
  const float* cw = (const float*)d_in[4];
  const float* cb = (const float*)d_in[5];
  const float* uf = (const float*)d_in[6];
  const float* df = (const float*)d_in[7];
  float* out = (float*)d_out;
  char* ws = (char*)d_ws;

  float* styles = (float*)(ws + 0);
  float* msr    = (float*)(ws + 16384);
  float* tbuf   = (float*)(ws + 16640);
  float* qbuf   = (float*)(ws + 18688);
  float* gbuf   = (float*)(ws + 1067264);
  unsigned short* xp   = (unsigned short*)(ws + 1083648);   // 37,879,808 B
  unsigned short* wbf2 = (unsigned short*)(ws + 38963456);  // 37,748,736 B
  float* yb            = (float*)(ws + 76712192);           // 71,368,704 B

  k_styles<<<16, 256, 0, stream>>>(w, aw, ab, styles);
  k_msr<<<1, 256, 0, stream>>>(styles, msr);
  k_wstat<<<512, 256, 0, stream>>>(cw, tbuf, qbuf);
  k_dmod<<<16, 256, 0, stream>>>(styles, msr, tbuf, qbuf, gbuf);
  k_wpack<<<512, 256, 0, stream>>>(cw, styles, msr, gbuf, wbf2);
  k_xpack<<<dim3(68, 8, 8), 256, 0, stream>>>(x, xp);
  k_conv<<<1120, 256, 0, stream>>>(xp, wbf2, cb, yb);
  k_updown<<<4096, 256, 0, stream>>>(yb, uf, df, out);
}

// Round 3
// 539.515 us; speedup vs baseline: 1.3990x; 1.2187x over previous
//
#include <hip/hip_runtime.h>

typedef __attribute__((ext_vector_type(4))) float floatx4;
typedef __attribute__((ext_vector_type(8))) short short8;

#define AS1(p) ((const __attribute__((address_space(1))) unsigned int*)(p))
#define AS3(p) ((__attribute__((address_space(3))) unsigned int*)(p))

static __device__ __forceinline__ void async16(const void* g, void* l) {
  __builtin_amdgcn_global_load_lds(AS1(g), AS3(l), 16, 0, 0);
}

static __device__ __forceinline__ unsigned short f2bf(float f) {
  unsigned u = __float_as_uint(f);
  unsigned r = u + 0x7FFFu + ((u >> 16) & 1u);
  return (unsigned short)(r >> 16);
}
static __device__ __forceinline__ unsigned packbf(float lo, float hi) {
  unsigned ul = __float_as_uint(lo), uh = __float_as_uint(hi);
  ul = ul + 0x7FFFu + ((ul >> 16) & 1u);
  uh = uh + 0x7FFFu + ((uh >> 16) & 1u);
  return (ul >> 16) | (uh & 0xFFFF0000u);
}
static __device__ __forceinline__ float bf2f(unsigned short h) {
  return __uint_as_float(((unsigned)h) << 16);
}
static __device__ __forceinline__ float bf_lo(unsigned u) { return __uint_as_float(u << 16); }
static __device__ __forceinline__ float bf_hi(unsigned u) { return __uint_as_float(u & 0xFFFF0000u); }

// ---------------------------------------------------------------- styles
__global__ void k_styles(const float* __restrict__ w, const float* __restrict__ aw,
                         const float* __restrict__ ab, float* __restrict__ styles) {
  int t = blockIdx.x * 256 + threadIdx.x;   // 4096
  int b = t >> 9, c = t & 511;
  float acc = 0.f;
  for (int d = 0; d < 512; ++d) acc += w[b * 512 + d] * aw[c * 512 + d];
  styles[t] = acc * 0.04419417382415922f + ab[c];
}

// ---------------------------------------------------------------- msr = rsqrt(mean(styles^2))
__global__ void k_msr(const float* __restrict__ styles, float* __restrict__ msr) {
  __shared__ float red[256];
  float acc = 0.f;
  for (int i = threadIdx.x; i < 4096; i += 256) { float v = styles[i]; acc += v * v; }
  red[threadIdx.x] = acc; __syncthreads();
  for (int s = 128; s > 0; s >>= 1) {
    if ((int)threadIdx.x < s) red[threadIdx.x] += red[threadIdx.x + s];
    __syncthreads();
  }
  if (threadIdx.x == 0) *msr = rsqrtf(red[0] / 4096.0f);
}

// ---------------------------------------------------------------- per-o weight stats
__global__ void k_wstat(const float* __restrict__ cw, float* __restrict__ t, float* __restrict__ q) {
  int o = blockIdx.x, tid = threadIdx.x;
  __shared__ float red[256];
  float tot = 0.f;
  for (int i = tid; i < 512; i += 256) {
    const float* p = cw + ((size_t)o * 512 + i) * 9;
    float s = 0.f;
#pragma unroll
    for (int k = 0; k < 9; ++k) s += p[k] * p[k];
    q[o * 512 + i] = s;
    tot += s;
  }
  red[tid] = tot; __syncthreads();
  for (int s2 = 128; s2 > 0; s2 >>= 1) {
    if (tid < s2) red[tid] += red[tid + s2];
    __syncthreads();
  }
  if (tid == 0) t[o] = rsqrtf(red[0] / 4608.0f);
}

// ---------------------------------------------------------------- g[b,o]
__global__ void k_dmod(const float* __restrict__ styles, const float* __restrict__ msr,
                       const float* __restrict__ t, const float* __restrict__ q,
                       float* __restrict__ g) {
  int idx = blockIdx.x * 256 + threadIdx.x;  // 4096
  int b = idx >> 9, o = idx & 511;
  float m = *msr;
  float acc = 0.f;
  for (int i = 0; i < 512; ++i) {
    float s = styles[b * 512 + i] * m;
    acc += s * s * q[o * 512 + i];
  }
  float to = t[o];
  g[idx] = to * rsqrtf(to * to * acc + 1e-8f);
}

// ---------------------------------------------------------------- wbf2: fragment-order packed bf16 weights
__global__ __launch_bounds__(256) void k_wpack(const float* __restrict__ cw,
                                               const float* __restrict__ styles,
                                               const float* __restrict__ msr,
                                               const float* __restrict__ g,
                                               unsigned short* __restrict__ wbf2) {
  __shared__ float raw[512][11];
  int o = blockIdx.x, tid = threadIdx.x;
  for (int i = tid; i < 512; i += 256) {
    const float* p = cw + ((size_t)o * 512 + i) * 9;
#pragma unroll
    for (int k = 0; k < 9; ++k) raw[i][k] = p[k];
  }
  __syncthreads();
  float m = *msr;
  const int nb = o >> 7, wn = (o >> 6) & 1, ni = (o >> 4) & 3, ol = o & 15;
  for (int b = 0; b < 8; ++b) {
    float gg = g[b * 512 + o];
    const size_t base_bo = ((size_t)(b * 4 + nb) * 2 + wn);
    for (int f = tid; f < 9 * 512; f += 256) {
      int s = f >> 9, i = f & 511;
      int ic = i >> 5, qq = (i >> 3) & 3, j = i & 7;
      float v = raw[i][s] * gg * (styles[b * 512 + i] * m);
      size_t idx = ((((base_bo * 9 + s) * 16 + ic) * 4 + ni) * 512) + (qq * 16 + ol) * 8 + j;
      wbf2[idx] = f2bf(v);
    }
  }
}

// ---------------------------------------------------------------- xp[b][Y][X][c] NHWC bf16 zero-padded (+2)
__global__ __launch_bounds__(256) void k_xpack(const float* __restrict__ x,
                                               unsigned short* __restrict__ xp) {
  __shared__ float tile[64][65];
  int Y = blockIdx.x, cc0 = blockIdx.y * 64, b = blockIdx.z;
  int tid = threadIdx.x;
  int yy = Y - 2;
  bool valid = (yy >= 0 && yy < 64);
  if (valid) {
    for (int it = 0; it < 16; ++it) {
      int f = it * 256 + tid;
      int cc = f >> 6, xx = f & 63;
      tile[xx][cc] = x[(((size_t)b * 512 + cc0 + cc) * 64 + yy) * 64 + xx];
    }
  }
  __syncthreads();
  for (int it = 0; it < 17; ++it) {
    int f = it * 256 + tid;   // < 68*64
    int X = f >> 6, cc = f & 63;
    int xx = X - 2;
    float v = (valid && xx >= 0 && xx < 64) ? tile[xx][cc] : 0.f;
    xp[(((size_t)b * 68 + Y) * 68 + X) * 512 + cc0 + cc] = f2bf(v);
  }
}

// ---------------------------------------------------------------- patch-based implicit-GEMM conv
__global__ __launch_bounds__(256, 2) void k_conv(const unsigned short* __restrict__ xp,
                                                 const unsigned short* __restrict__ wbf2,
                                                 const float* __restrict__ cb,
                                                 float* __restrict__ y) {
  __shared__ __align__(16) unsigned short lds[24576];
  const int tid = threadIdx.x;
  const int w = tid >> 6, lane = tid & 63;
  const int wm = w & 1, wn = w >> 1;
  const int q = lane >> 4, ln = lane & 15;

  const int xcd = blockIdx.x & 7;
  const int slot = blockIdx.x >> 3;
  const int combo = xcd * 4 + slot / 35;
  const int mt = slot % 35;
  const int nt = combo & 3;
  const int b = combo >> 2;
  const int m0 = mt * 128, n0 = nt * 128;
  const int oy0 = m0 / 66;

  const unsigned short* xpb = xp + (size_t)b * (68 * 68 * 512);

  size_t gof_p[6];
#pragma unroll
  for (int i = 0; i < 6; ++i) {
    int pv = w * 96 + i * 16 + (lane >> 2);
    int pve = pv < 339 ? pv : 339;
    int r = pve / 68, px = pve - r * 68;
    int Y = oy0 + r; if (Y > 67) Y = 67;
    int ch = ((lane & 3) ^ ((pve >> 1) & 3)) * 8;
    gof_p[i] = (size_t)(Y * 68 + px) * 512 + ch;
  }

  int pvA[4];
#pragma unroll
  for (int mi = 0; mi < 4; ++mi) {
    int p = m0 + wm * 64 + mi * 16 + ln; if (p > 4355) p = 4355;
    int oy = p / 66, ox = p - oy * 66;
    pvA[mi] = (oy - oy0) * 68 + ox;
  }

  const unsigned short* wB = wbf2 + (((size_t)(b * 4 + nt) * 2 + wn) * 294912) + (size_t)lane * 8;

  floatx4 acc[4][4];
#pragma unroll
  for (int i = 0; i < 4; ++i)
#pragma unroll
    for (int j = 0; j < 4; ++j) acc[i][j] = (floatx4){0.f, 0.f, 0.f, 0.f};

  unsigned short* pat0 = lds;
  unsigned short* pat1 = lds + 12288;

#pragma unroll
  for (int i = 0; i < 6; ++i)
    async16(xpb + gof_p[i], pat0 + (w * 96 + i * 16) * 32);

  short8 bF[4];
#pragma unroll
  for (int ni = 0; ni < 4; ++ni)
    bF[ni] = *(const short8*)(wB + ni * 512);

  for (int ic = 0; ic < 16; ++ic) {
    asm volatile("s_waitcnt vmcnt(0)" ::: "memory");
    asm volatile("s_barrier" ::: "memory");
    const unsigned short* pb = (ic & 1) ? pat1 : pat0;
    unsigned short* pn = (ic & 1) ? pat0 : pat1;
    const size_t pchan = (size_t)(ic + 1) * 32;
#pragma unroll
    for (int s = 0; s < 9; ++s) {
      if (s >= 1 && s <= 6 && ic < 15)
        async16(xpb + gof_p[s - 1] + pchan, pn + (w * 96 + (s - 1) * 16) * 32);
      const int sn = (s < 8) ? s + 1 : 0;
      const int icn = (s < 8) ? ic : (ic < 15 ? ic + 1 : 15);
      const unsigned short* wBn = wB + ((size_t)sn * 16 + icn) * 2048;
      short8 bN[4];
#pragma unroll
      for (int ni = 0; ni < 4; ++ni) bN[ni] = *(const short8*)(wBn + ni * 512);
      const int d = (s / 3) * 68 + (s % 3);
      short8 aF[4];
#pragma unroll
      for (int mi = 0; mi < 4; ++mi) {
        int pv = pvA[mi] + d;
        int off = pv * 32 + ((q ^ ((pv >> 1) & 3)) << 3);
        aF[mi] = *(const short8*)(pb + off);
      }
#pragma unroll
      for (int mi = 0; mi < 4; ++mi)
#pragma unroll
        for (int ni = 0; ni < 4; ++ni)
          acc[mi][ni] = __builtin_amdgcn_mfma_f32_16x16x32_bf16(aF[mi], bF[ni], acc[mi][ni], 0, 0, 0);
#pragma unroll
      for (int ni = 0; ni < 4; ++ni) bF[ni] = bN[ni];
    }
  }

  __syncthreads();
  float* slab = (float*)lds + w * 2176;
  const int pbase = m0 + wm * 64;
  const bool pok = (pbase + ln * 4) < 4356;
  float cbv[4];
#pragma unroll
  for (int ni = 0; ni < 4; ++ni) cbv[ni] = cb[n0 + wn * 64 + ni * 16 + ln];

#pragma unroll
  for (int pass = 0; pass < 2; ++pass) {
#pragma unroll
    for (int ni2 = 0; ni2 < 2; ++ni2) {
      const int ni = pass * 2 + ni2;
#pragma unroll
      for (int mi = 0; mi < 4; ++mi) {
        float4 v;
        v.x = acc[mi][ni][0] + cbv[ni];
        v.y = acc[mi][ni][1] + cbv[ni];
        v.z = acc[mi][ni][2] + cbv[ni];
        v.w = acc[mi][ni][3] + cbv[ni];
        *(float4*)&slab[(ni2 * 16 + ln) * 68 + mi * 16 + q * 4] = v;
      }
    }
#pragma unroll
    for (int i = 0; i < 8; ++i) {
      const int orow = i * 4 + q;
      const int o = n0 + wn * 64 + pass * 32 + orow;
      if (pok) {
        float4 vv = *(const float4*)&slab[orow * 68 + ln * 4];
        *(float4*)&y[((size_t)b * 512 + o) * 4356 + pbase + ln * 4] = vv;
      }
    }
  }
}

// ---------------------------------------------------------------- fused up/act/down, strip-vectorized
// grid: 8192 = 4096 planes x 2 x-strips (32 out cols each)
// LDS: zbuf 138x88 bf16 (24288B, ybuf fp32 75x48 overlaid) + t1 138x56 bf16 (15456B, t2 64x88 overlaid)
__global__ __launch_bounds__(256, 4) void k_updown(const float* __restrict__ yg,
                                                   const float* __restrict__ uf,
                                                   const float* __restrict__ df,
                                                   float* __restrict__ out) {
  __shared__ __align__(16) unsigned short zraw[138 * 88];
  __shared__ __align__(16) unsigned short t1buf[138 * 56];
  const int tid = threadIdx.x;
  const int plane = blockIdx.x >> 1;
  const int s = blockIdx.x & 1;
  const float* yp = yg + (size_t)plane * 4356;

  float fub[12], fuc[12], fdw[12];
#pragma unroll
  for (int i = 0; i < 12; ++i) {
    float u = uf[11 - i] * 2.0f;
    fub[i] = u;
    fuc[i] = u * 1.41421356237309515f;  // GAIN folded into stage-C taps (leaky is pos-homogeneous)
    fdw[i] = df[11 - i];
  }

  // ---- Stage A: y strip -> LDS fp32, zero-padded. rows 0..74 <-> y rows -4..70; cols local 0..47
  float* ybuf = (float*)zraw;
  const int xoff = 32 * s - 4;
  for (int t = tid; t < 75 * 48; t += 256) {
    int row = t / 48, col = t - row * 48;
    int r = row - 4, x = xoff + col;
    float v = (r >= 0 && r < 66 && x >= 0 && x < 66) ? yp[r * 66 + x] : 0.f;
    ybuf[t] = v;
  }
  __syncthreads();

  // ---- Stage B: up-y. 69 v-pairs x 6 chunks-of-8 cols -> t1 (138 rows x 56 pitch bf16)
  for (int t = tid; t < 69 * 6; t += 256) {
    int v = t / 6, c = t - v * 6;
    float ae[8], ao[8];
#pragma unroll
    for (int e = 0; e < 8; ++e) { ae[e] = 0.f; ao[e] = 0.f; }
#pragma unroll
    for (int u = 0; u < 6; ++u) {
      const float* yr = &ybuf[(v + u) * 48 + 8 * c];
      float4 p0 = *(const float4*)yr;
      float4 p1 = *(const float4*)(yr + 4);
      float fe = fub[2 * u + 1], fo = fub[2 * u];
      ae[0] += p0.x * fe; ao[0] += p0.x * fo;
      ae[1] += p0.y * fe; ao[1] += p0.y * fo;
      ae[2] += p0.z * fe; ao[2] += p0.z * fo;
      ae[3] += p0.w * fe; ao[3] += p0.w * fo;
      ae[4] += p1.x * fe; ao[4] += p1.x * fo;
      ae[5] += p1.y * fe; ao[5] += p1.y * fo;
      ae[6] += p1.z * fe; ao[6] += p1.z * fo;
      ae[7] += p1.w * fe; ao[7] += p1.w * fo;
    }
    uint4 se, so;
    se.x = packbf(ae[0], ae[1]); se.y = packbf(ae[2], ae[3]);
    se.z = packbf(ae[4], ae[5]); se.w = packbf(ae[6], ae[7]);
    so.x = packbf(ao[0], ao[1]); so.y = packbf(ao[2], ao[3]);
    so.z = packbf(ao[4], ao[5]); so.w = packbf(ao[6], ao[7]);
    *(uint4*)&t1buf[(2 * v) * 56 + 8 * c] = se;
    *(uint4*)&t1buf[(2 * v + 1) * 56 + 8 * c] = so;
  }
  __syncthreads();

  // ---- Stage C: up-x + act. 138 rows x 5 chunks-of-16 z cols -> zbuf (138 x 88 pitch bf16)
  for (int t = tid; t < 138 * 5; t += 256) {
    int Y = t / 5, k = t - Y * 5;
    const unsigned short* tr = &t1buf[Y * 56 + 8 * k];
    uint4 r0 = *(const uint4*)tr;
    uint4 r1 = *(const uint4*)(tr + 8);
    float a[14];
    a[0] = bf_lo(r0.x);  a[1] = bf_hi(r0.x);
    a[2] = bf_lo(r0.y);  a[3] = bf_hi(r0.y);
    a[4] = bf_lo(r0.z);  a[5] = bf_hi(r0.z);
    a[6] = bf_lo(r0.w);  a[7] = bf_hi(r0.w);
    a[8] = bf_lo(r1.x);  a[9] = bf_hi(r1.x);
    a[10] = bf_lo(r1.y); a[11] = bf_hi(r1.y);
    a[12] = bf_lo(r1.z); a[13] = bf_hi(r1.z);
    float ae[8], ao[8];
#pragma unroll
    for (int p = 0; p < 8; ++p) { ae[p] = 0.f; ao[p] = 0.f; }
#pragma unroll
    for (int u = 0; u < 6; ++u) {
      float fe = fuc[2 * u + 1], fo = fuc[2 * u];
#pragma unroll
      for (int p = 0; p < 8; ++p) {
        float tv = a[p + u];
        ae[p] += tv * fe;
        ao[p] += tv * fo;
      }
    }
    uint4 s0, s1;
    float ze[8], zo[8];
#pragma unroll
    for (int p = 0; p < 8; ++p) {
      float v0 = fmaxf(ae[p], 0.f) + 0.2f * fminf(ae[p], 0.f);
      float v1 = fmaxf(ao[p], 0.f) + 0.2f * fminf(ao[p], 0.f);
      ze[p] = fminf(fmaxf(v0, -256.f), 256.f);
      zo[p] = fminf(fmaxf(v1, -256.f), 256.f);
    }
    s0.x = packbf(ze[0], zo[0]); s0.y = packbf(ze[1], zo[1]);
    s0.z = packbf(ze[2], zo[2]); s0.w = packbf(ze[3], zo[3]);
    s1.x = packbf(ze[4], zo[4]); s1.y = packbf(ze[5], zo[5]);
    s1.z = packbf(ze[6], zo[6]); s1.w = packbf(ze[7], zo[7]);
    unsigned short* zr = &zraw[Y * 88 + 16 * k];
    *(uint4*)zr = s0;
    *(uint4*)(zr + 8) = s1;
  }
  __syncthreads();

  // ---- Stage D: down-y. 64 rows x 10 chunks-of-8 -> t2 (overlay t1buf, 64 x 88 pitch bf16)
  unsigned short* t2 = t1buf;
  for (int t = tid; t < 64 * 10; t += 256) {
    int yr = t / 10, k = t - yr * 10;
    float acc[8];
#pragma unroll
    for (int e = 0; e < 8; ++e) acc[e] = 0.f;
#pragma unroll
    for (int i = 0; i < 12; ++i) {
      uint4 zv = *(const uint4*)&zraw[(2 * yr + i) * 88 + 8 * k];
      float c = fdw[i];
      acc[0] += c * bf_lo(zv.x); acc[1] += c * bf_hi(zv.x);
      acc[2] += c * bf_lo(zv.y); acc[3] += c * bf_hi(zv.y);
      acc[4] += c * bf_lo(zv.z); acc[5] += c * bf_hi(zv.z);
      acc[6] += c * bf_lo(zv.w); acc[7] += c * bf_hi(zv.w);
    }
    uint4 st;
    st.x = packbf(acc[0], acc[1]); st.y = packbf(acc[2], acc[3]);
    st.z = packbf(acc[4], acc[5]); st.w = packbf(acc[6], acc[7]);
    *(uint4*)&t2[yr * 88 + 8 * k] = st;
  }
  __syncthreads();

  // ---- Stage E: down-x. 64 rows x 4 chunks-of-8 out cols; exactly 1 task/thread
  {
    int t = tid;                      // 256 = 64*4
    int yr = t >> 2, ce = t & 3;
    const unsigned short* tr = &t2[yr * 88 + 16 * ce];
    uint4 q0 = *(const uint4*)tr;
    uint4 q1 = *(const uint4*)(tr + 8);
    uint4 q2 = *(const uint4*)(tr + 16);
    uint4 q3 = *(const uint4*)(tr + 24);
    float wv[26];
    wv[0] = bf_lo(q0.x);  wv[1] = bf_hi(q0.x);
    wv[2] = bf_lo(q0.y);  wv[3] = bf_hi(q0.y);
    wv[4] = bf_lo(q0.z);  wv[5] = bf_hi(q0.z);
    wv[6] = bf_lo(q0.w);  wv[7] = bf_hi(q0.w);
    wv[8] = bf_lo(q1.x);  wv[9] = bf_hi(q1.x);
    wv[10] = bf_lo(q1.y); wv[11] = bf_hi(q1.y);
    wv[12] = bf_lo(q1.z); wv[13] = bf_hi(q1.z);
    wv[14] = bf_lo(q1.w); wv[15] = bf_hi(q1.w);
    wv[16] = bf_lo(q2.x); wv[17] = bf_hi(q2.x);
    wv[18] = bf_lo(q2.y); wv[19] = bf_hi(q2.y);
    wv[20] = bf_lo(q2.z); wv[21] = bf_hi(q2.z);
    wv[22] = bf_lo(q2.w); wv[23] = bf_hi(q2.w);
    wv[24] = bf_lo(q3.x); wv[25] = bf_hi(q3.x);
    float ov[8];
#pragma unroll
    for (int e = 0; e < 8; ++e) {
      float acc = 0.f;
#pragma unroll
      for (int j = 0; j < 12; ++j) acc += fdw[j] * wv[2 * e + j];
      ov[e] = acc;
    }
    float* op = out + (size_t)plane * 4096 + yr * 64 + 32 * s + 8 * ce;
    *(float4*)op = (float4){ov[0], ov[1], ov[2], ov[3]};
    *(float4*)(op + 4) = (float4){ov[4], ov[5], ov[6], ov[7]};
  }
}

extern "C" void kernel_launch(void* const* d_in, const int* in_sizes, int n_in,
                              void* d_out, int out_size, void* d_ws, size_t ws_size,
                              hipStream_t stream) {
  const float* x  = (const float*)d_in[0];
  const float* w  = (const float*)d_in[1];
  const float* aw = (const float*)d_in[2];
  const float* ab = (const float*)d_in[3];
  const float* cw = (const float*)d_in[4];
  const float* cb = (const float*)d_in[5];
  const float* uf = (const float*)d_in[6];
  const float* df = (const float*)d_in[7];
  float* out = (float*)d_out;
  char* ws = (char*)d_ws;

  float* styles = (float*)(ws + 0);
  float* msr    = (float*)(ws + 16384);
  float* tbuf   = (float*)(ws + 16640);
  float* qbuf   = (float*)(ws + 18688);
  float* gbuf   = (float*)(ws + 1067264);
  unsigned short* xp   = (unsigned short*)(ws + 1083648);
  unsigned short* wbf2 = (unsigned short*)(ws + 38963456);
  float* yb            = (float*)(ws + 76712192);

  k_styles<<<16, 256, 0, stream>>>(w, aw, ab, styles);
  k_msr<<<1, 256, 0, stream>>>(styles, msr);
  k_wstat<<<512, 256, 0, stream>>>(cw, tbuf, qbuf);
  k_dmod<<<16, 256, 0, stream>>>(styles, msr, tbuf, qbuf, gbuf);
  k_wpack<<<512, 256, 0, stream>>>(cw, styles, msr, gbuf, wbf2);
  k_xpack<<<dim3(68, 8, 8), 256, 0, stream>>>(x, xp);
  k_conv<<<1120, 256, 0, stream>>>(xp, wbf2, cb, yb);
  k_updown<<<8192, 256, 0, stream>>>(yb, uf, df, out);
}